// Round 19
// baseline (32.083 us; speedup 1.0000x reference)
//
#include <hip/hip_runtime.h>
#include <hip/hip_bf16.h>

namespace {

// may_alias everywhere LDS/out is accessed through more than one type.
typedef short bf16x8 __attribute__((ext_vector_type(8), may_alias));
typedef unsigned long long u64_ma __attribute__((may_alias));
typedef float f32x4_ma __attribute__((ext_vector_type(4), may_alias));
typedef __attribute__((ext_vector_type(16))) float f32x16;   // MFMA 32x32 acc

constexpr int kB = 32, kT = 16384, kCin = 32, kCout = 32;
constexpr int kL = 128;            // owned rows per chunk
constexpr int kK = 32;             // zero-state warm-up
constexpr int kChunks = kT / kL;   // 128
constexpr int kWpB = 4;            // waves per block
constexpr int kRS = 80;            // LDS bf16 row stride: 64B data + 16B pad
constexpr int kStageRows = 34;     // 32 rows + 2 halo rows
constexpr int kStageB = kStageRows * kRS;  // 2720 B per stage
constexpr int kNT = 5;             // 1 warm-up tile + 4 owned tiles
constexpr int kTS = 36;            // transpose-buffer row stride (floats)
constexpr int kTBufB = 32 * kTS * 4;       // 4608 B per wave
constexpr int kNXCD = 8;
constexpr int kGrid = kB * kChunks / kWpB; // 1024 blocks (1024 % 8 == 0)

__device__ __forceinline__ unsigned bfbits(float f) {
  return (unsigned)__builtin_bit_cast(unsigned short, __float2bfloat16(f));
}

// R18 (28.8 us) + XCD-aware block swizzle (T1): adjacent chunks share 27% of
// their u reads (warm-up halo = neighbor's owned rows). Default round-robin
// dispatch puts neighbors on different XCDs -> halo re-reads miss the private
// L2. Contiguous-per-XCD remap makes them L2 hits. Everything else identical.
__global__ __launch_bounds__(256, 4) void mimo_mfma14(
    const float* __restrict__ u,        // [B, T, CIN]
    const float* __restrict__ x0,       // [B, 2, COUT]
    const float* __restrict__ a_coeff,  // [2, COUT]
    const float* __restrict__ b_coeff,  // [3, CIN, COUT]
    float* __restrict__ out)            // [B, T, COUT]
{
  __shared__ char stage[kWpB][kStageB];   // 10.6 KiB
  __shared__ char tbuf[kWpB][kTBufB];     // 18.0 KiB

  const int tidx = (int)threadIdx.x;
  const int lane = tidx & 63;
  const int col  = lane & 31;          // output channel / time-row within tile
  const int g    = lane >> 5;          // lane-half
  const int widx = tidx >> 6;
  // XCD swizzle: HW assigns block n -> XCD n%8; remap so each XCD owns a
  // CONTIGUOUS sbid range (bijective since kGrid % 8 == 0).
  const int bid  = (int)blockIdx.x;
  const int sbid = (bid & (kNXCD - 1)) * (kGrid / kNXCD) + (bid >> 3);
  const int wid  = sbid * kWpB + widx;
  const int b     = wid >> 7;          // 0..31
  const int chunk = wid & (kChunks - 1);
  const int t0     = chunk * kL;
  const int tstart = t0 - kK;          // unified: chunk 0 warms over zero-pad

  char* Sw = &stage[widx][0];
  float* Tw = (float*)&tbuf[widx][0];

  // B fragments: slot (g,j) of K-step (tau,h) = b_coeff[2-tau][16g+8h+j][col].
  // A uses the SAME slot->channel map, so the HW k-order cancels.
  bf16x8 Bf[3][2];
#pragma unroll
  for (int tau = 0; tau < 3; ++tau)
#pragma unroll
    for (int h = 0; h < 2; ++h) {
      const float* bp = b_coeff + (size_t)(2 - tau) * kCin * kCout
                        + (16 * g + 8 * h) * kCout + col;
      bf16x8 fr;
#pragma unroll
      for (int j = 0; j < 8; ++j)
        fr[j] = (short)__builtin_bit_cast(unsigned short, __float2bfloat16(bp[j * kCout]));
      Bf[tau][h] = fr;
    }

  const float a1 = a_coeff[col];
  const float a2 = a_coeff[kCout + col];
  // chunk-0 exact initial state, injected at the first owned tile (warm-up
  // over zero-padded u leaves the state at exactly 0 for chunk 0).
  float i1 = 0.f, i2 = 0.f;
  if (chunk == 0) {
    i1 = x0[(b * 2 + 1) * kCout + col];
    i2 = x0[(b * 2 + 0) * kCout + col];
  }
  float s1 = 0.f, s2 = 0.f;

  const float* ub = u + (size_t)b * kT * kCin;
  float* ob = out + (size_t)b * kT * kCout;

  // Coalesced stage load: f4-index f of a 34-row stage starting at rowbase.
  auto gload = [&](int rowbase, int f) -> float4 {
    const int grow = rowbase + (f >> 3);
    if (grow >= 0)
      return *(const float4*)(ub + (size_t)grow * kCin + ((f & 7) << 2));
    float4 z; z.x = 0.f; z.y = 0.f; z.z = 0.f; z.w = 0.f;
    return z;
  };
  // cvt f32x4 -> bf16x4 and ds_write_b64 into the 80B-stride stage.
  auto stash = [&](int f, float4 v) {
    const unsigned lo = bfbits(v.x) | (bfbits(v.y) << 16);
    const unsigned hi = bfbits(v.z) | (bfbits(v.w) << 16);
    const unsigned long long q = ((unsigned long long)hi << 32) | lo;
    *(u64_ma*)(Sw + (f >> 3) * kRS + (f & 7) * 8) = q;
  };

  // -------- prologue: stage rows [tstart-2, tstart+32) --------
  {
    const int rowbase = tstart - 2;   // negative rows staged as zeros
    float4 p0 = gload(rowbase, lane);
    float4 p1 = gload(rowbase, lane + 64);
    float4 p2 = gload(rowbase, lane + 128);
    float4 p3 = gload(rowbase, lane + 192);
    float4 p4;
    if (lane < 16) p4 = gload(rowbase, lane + 256);
    stash(lane, p0);
    stash(lane + 64, p1);
    stash(lane + 128, p2);
    stash(lane + 192, p3);
    if (lane < 16) stash(lane + 256, p4);
  }
  asm volatile("" ::: "memory");   // stage writes ordered before tile-0 reads

#pragma unroll
  for (int tile = 0; tile < kNT; ++tile) {
    const int tbase = tstart + 32 * tile;
    const bool last = (tile + 1 == kNT);
    const bool owned = (tile >= 1);      // tile 0 is the warm-up tile

    // issue-early: next stage's coalesced global loads fly during compute.
    float4 n0, n1, n2, n3, n4;
    if (!last) {
      const int rowbase = tbase + 30;   // (tbase+32) - 2
      n0 = gload(rowbase, lane);
      n1 = gload(rowbase, lane + 64);
      n2 = gload(rowbase, lane + 128);
      n3 = gload(rowbase, lane + 192);
      if (lane < 16) n4 = gload(rowbase, lane + 256);
    }

    // ---- FIR: 6x ds_read_b128 (bf16 direct) + 6 MFMAs ----
    f32x16 acc;
#pragma unroll
    for (int i = 0; i < 16; ++i) acc[i] = 0.f;
#pragma unroll
    for (int tau = 0; tau < 3; ++tau) {
      const char* rp = Sw + (col + tau) * kRS + 32 * g;
#pragma unroll
      for (int h = 0; h < 2; ++h) {
        const bf16x8 fa = *(const bf16x8*)(rp + 16 * h);
        acc = __builtin_amdgcn_mfma_f32_32x32x16_bf16(fa, Bf[tau][h], acc, 0, 0, 0);
      }
    }

    // chunk-0 exact state injection at the first owned tile.
    if (chunk == 0 && tile == 1) { s1 = i1; s2 = i2; }

    // ---- IIR per reg-quad (R11-proven chain); results go to the LDS
    // transpose buffer. Lane (col,g) writes rows 8q+4g+0..3.
    // Reg r (half gg) holds row (r&3) + 8*(r>>2) + 4*gg of the tile.
    float x1 = s1, x2 = s2;
#pragma unroll
    for (int q = 0; q < 4; ++q) {
      const float o0 = __shfl_xor(acc[4 * q + 0], 32);
      const float o1 = __shfl_xor(acc[4 * q + 1], 32);
      const float o2 = __shfl_xor(acc[4 * q + 2], 32);
      const float o3 = __shfl_xor(acc[4 * q + 3], 32);
      const float va0 = g ? o0 : acc[4 * q + 0];
      const float va1 = g ? o1 : acc[4 * q + 1];
      const float va2 = g ? o2 : acc[4 * q + 2];
      const float va3 = g ? o3 : acc[4 * q + 3];
      const float ya0 = fmaf(a1, x1,  fmaf(a2, x2,  va0));
      const float ya1 = fmaf(a1, ya0, fmaf(a2, x1,  va1));
      const float ya2 = fmaf(a1, ya1, fmaf(a2, ya0, va2));
      const float ya3 = fmaf(a1, ya2, fmaf(a2, ya1, va3));
      const float vb0 = g ? acc[4 * q + 0] : o0;
      const float vb1 = g ? acc[4 * q + 1] : o1;
      const float vb2 = g ? acc[4 * q + 2] : o2;
      const float vb3 = g ? acc[4 * q + 3] : o3;
      const float yb0 = fmaf(a1, ya3, fmaf(a2, ya2, vb0));
      const float yb1 = fmaf(a1, yb0, fmaf(a2, ya3, vb1));
      const float yb2 = fmaf(a1, yb1, fmaf(a2, yb0, vb2));
      const float yb3 = fmaf(a1, yb2, fmaf(a2, yb1, vb3));
      x2 = yb2; x1 = yb3;
      if (owned) {
        const int rb = 8 * q + 4 * g;   // lane half g writes rows rb..rb+3
        Tw[(rb + 0) * kTS + col] = g ? yb0 : ya0;
        Tw[(rb + 1) * kTS + col] = g ? yb1 : ya1;
        Tw[(rb + 2) * kTS + col] = g ? yb2 : ya2;
        Tw[(rb + 3) * kTS + col] = g ? yb3 : ya3;
      }
    }
    s1 = x1; s2 = x2;

    // ---- emit: 4x ds_read_b128 + 4x full-wave NON-TEMPORAL dwordx4 stores.
    if (owned) {
      asm volatile("" ::: "memory");   // transpose writes before reads
#pragma unroll
      for (int p = 0; p < 4; ++p) {
        const f32x4_ma v = *(const f32x4_ma*)
            ((const char*)Tw + (8 * p + (lane >> 3)) * (kTS * 4) + (lane & 7) * 16);
        __builtin_nontemporal_store(
            v, (f32x4_ma*)(ob + (size_t)(tbase + 8 * p) * kCout + lane * 4));
      }
      asm volatile("" ::: "memory");   // reads before next tile's writes
    }

    // write-late stage refill (wave-local, in-order DS).
    if (!last) {
      asm volatile("" ::: "memory");   // this tile's ds_reads issue first
      stash(lane, n0);
      stash(lane + 64, n1);
      stash(lane + 128, n2);
      stash(lane + 192, n3);
      if (lane < 16) stash(lane + 256, n4);
      asm volatile("" ::: "memory");   // refill before next tile's ds_reads
    }
  }
}

}  // namespace

extern "C" void kernel_launch(void* const* d_in, const int* in_sizes, int n_in,
                              void* d_out, int out_size, void* d_ws, size_t ws_size,
                              hipStream_t stream) {
  const float* u  = (const float*)d_in[0];
  const float* x0 = (const float*)d_in[1];
  const float* a  = (const float*)d_in[2];
  const float* bb = (const float*)d_in[3];
  float* out = (float*)d_out;

  dim3 grid(kGrid);   // 1024 blocks
  dim3 block(256);
  hipLaunchKernelGGL(mimo_mfma14, grid, block, 0, stream, u, x0, a, bb, out);
}

// Round 21
// 28.921 us; speedup vs baseline: 1.1093x; 1.1093x over previous
//
#include <hip/hip_runtime.h>
#include <hip/hip_bf16.h>

namespace {

// may_alias everywhere LDS/out is accessed through more than one type.
typedef short bf16x8 __attribute__((ext_vector_type(8), may_alias));
typedef unsigned long long u64_ma __attribute__((may_alias));
typedef float f32x4_ma __attribute__((ext_vector_type(4), may_alias));
typedef __attribute__((ext_vector_type(16))) float f32x16;   // MFMA 32x32 acc

constexpr int kB = 32, kT = 16384, kCin = 32, kCout = 32;
constexpr int kL = 128;            // owned rows per chunk
constexpr int kK = 32;             // zero-state warm-up
constexpr int kChunks = kT / kL;   // 128
constexpr int kWpB = 4;            // waves per block
constexpr int kRS = 80;            // LDS bf16 row stride: 64B data + 16B pad
constexpr int kStageRows = 34;     // 32 rows + 2 halo rows
constexpr int kStageB = kStageRows * kRS;  // 2720 B per stage
constexpr int kNT = 5;             // 1 warm-up tile + 4 owned tiles
constexpr int kTS = 36;            // transpose-buffer row stride (floats)
constexpr int kTBufB = 32 * kTS * 4;       // 4608 B per wave

__device__ __forceinline__ unsigned bfbits(float f) {
  return (unsigned)__builtin_bit_cast(unsigned short, __float2bfloat16(f));
}

// R18 exactly (best: 28.8 us): R13 structure + non-temporal output stores.
// 15 structural experiments bracket this point (see session ledger); the
// shfl_xor half-exchange is the PROVEN exchange (permlane32_swap semantics
// unverifiable on this toolchain — two mismatched-output failures).
__global__ __launch_bounds__(256, 4) void mimo_mfma13(
    const float* __restrict__ u,        // [B, T, CIN]
    const float* __restrict__ x0,       // [B, 2, COUT]
    const float* __restrict__ a_coeff,  // [2, COUT]
    const float* __restrict__ b_coeff,  // [3, CIN, COUT]
    float* __restrict__ out)            // [B, T, COUT]
{
  __shared__ char stage[kWpB][kStageB];   // 10.6 KiB
  __shared__ char tbuf[kWpB][kTBufB];     // 18.0 KiB

  const int tidx = (int)threadIdx.x;
  const int lane = tidx & 63;
  const int col  = lane & 31;          // output channel / time-row within tile
  const int g    = lane >> 5;          // lane-half
  const int widx = tidx >> 6;
  const int wid  = (int)blockIdx.x * kWpB + widx;
  const int b     = wid >> 7;          // 0..31
  const int chunk = wid & (kChunks - 1);
  const int t0     = chunk * kL;
  const int tstart = t0 - kK;          // unified: chunk 0 warms over zero-pad

  char* Sw = &stage[widx][0];
  float* Tw = (float*)&tbuf[widx][0];

  // B fragments: slot (g,j) of K-step (tau,h) = b_coeff[2-tau][16g+8h+j][col].
  // A uses the SAME slot->channel map, so the HW k-order cancels.
  bf16x8 Bf[3][2];
#pragma unroll
  for (int tau = 0; tau < 3; ++tau)
#pragma unroll
    for (int h = 0; h < 2; ++h) {
      const float* bp = b_coeff + (size_t)(2 - tau) * kCin * kCout
                        + (16 * g + 8 * h) * kCout + col;
      bf16x8 fr;
#pragma unroll
      for (int j = 0; j < 8; ++j)
        fr[j] = (short)__builtin_bit_cast(unsigned short, __float2bfloat16(bp[j * kCout]));
      Bf[tau][h] = fr;
    }

  const float a1 = a_coeff[col];
  const float a2 = a_coeff[kCout + col];
  // chunk-0 exact initial state, injected at the first owned tile (warm-up
  // over zero-padded u leaves the state at exactly 0 for chunk 0).
  float i1 = 0.f, i2 = 0.f;
  if (chunk == 0) {
    i1 = x0[(b * 2 + 1) * kCout + col];
    i2 = x0[(b * 2 + 0) * kCout + col];
  }
  float s1 = 0.f, s2 = 0.f;

  const float* ub = u + (size_t)b * kT * kCin;
  float* ob = out + (size_t)b * kT * kCout;

  // Coalesced stage load: f4-index f of a 34-row stage starting at rowbase.
  auto gload = [&](int rowbase, int f) -> float4 {
    const int grow = rowbase + (f >> 3);
    if (grow >= 0)
      return *(const float4*)(ub + (size_t)grow * kCin + ((f & 7) << 2));
    float4 z; z.x = 0.f; z.y = 0.f; z.z = 0.f; z.w = 0.f;
    return z;
  };
  // cvt f32x4 -> bf16x4 and ds_write_b64 into the 80B-stride stage.
  auto stash = [&](int f, float4 v) {
    const unsigned lo = bfbits(v.x) | (bfbits(v.y) << 16);
    const unsigned hi = bfbits(v.z) | (bfbits(v.w) << 16);
    const unsigned long long q = ((unsigned long long)hi << 32) | lo;
    *(u64_ma*)(Sw + (f >> 3) * kRS + (f & 7) * 8) = q;
  };

  // -------- prologue: stage rows [tstart-2, tstart+32) --------
  {
    const int rowbase = tstart - 2;   // negative rows staged as zeros
    float4 p0 = gload(rowbase, lane);
    float4 p1 = gload(rowbase, lane + 64);
    float4 p2 = gload(rowbase, lane + 128);
    float4 p3 = gload(rowbase, lane + 192);
    float4 p4;
    if (lane < 16) p4 = gload(rowbase, lane + 256);
    stash(lane, p0);
    stash(lane + 64, p1);
    stash(lane + 128, p2);
    stash(lane + 192, p3);
    if (lane < 16) stash(lane + 256, p4);
  }
  asm volatile("" ::: "memory");   // stage writes ordered before tile-0 reads

#pragma unroll
  for (int tile = 0; tile < kNT; ++tile) {
    const int tbase = tstart + 32 * tile;
    const bool last = (tile + 1 == kNT);
    const bool owned = (tile >= 1);      // tile 0 is the warm-up tile

    // issue-early: next stage's coalesced global loads fly during compute.
    float4 n0, n1, n2, n3, n4;
    if (!last) {
      const int rowbase = tbase + 30;   // (tbase+32) - 2
      n0 = gload(rowbase, lane);
      n1 = gload(rowbase, lane + 64);
      n2 = gload(rowbase, lane + 128);
      n3 = gload(rowbase, lane + 192);
      if (lane < 16) n4 = gload(rowbase, lane + 256);
    }

    // ---- FIR: 6x ds_read_b128 (bf16 direct) + 6 MFMAs ----
    f32x16 acc;
#pragma unroll
    for (int i = 0; i < 16; ++i) acc[i] = 0.f;
#pragma unroll
    for (int tau = 0; tau < 3; ++tau) {
      const char* rp = Sw + (col + tau) * kRS + 32 * g;
#pragma unroll
      for (int h = 0; h < 2; ++h) {
        const bf16x8 fa = *(const bf16x8*)(rp + 16 * h);
        acc = __builtin_amdgcn_mfma_f32_32x32x16_bf16(fa, Bf[tau][h], acc, 0, 0, 0);
      }
    }

    // chunk-0 exact state injection at the first owned tile.
    if (chunk == 0 && tile == 1) { s1 = i1; s2 = i2; }

    // ---- IIR per reg-quad (proven chain); results go to the LDS
    // transpose buffer. Lane (col,g) writes rows 8q+4g+0..3.
    // Reg r (half gg) holds row (r&3) + 8*(r>>2) + 4*gg of the tile.
    float x1 = s1, x2 = s2;
#pragma unroll
    for (int q = 0; q < 4; ++q) {
      const float o0 = __shfl_xor(acc[4 * q + 0], 32);
      const float o1 = __shfl_xor(acc[4 * q + 1], 32);
      const float o2 = __shfl_xor(acc[4 * q + 2], 32);
      const float o3 = __shfl_xor(acc[4 * q + 3], 32);
      const float va0 = g ? o0 : acc[4 * q + 0];
      const float va1 = g ? o1 : acc[4 * q + 1];
      const float va2 = g ? o2 : acc[4 * q + 2];
      const float va3 = g ? o3 : acc[4 * q + 3];
      const float ya0 = fmaf(a1, x1,  fmaf(a2, x2,  va0));
      const float ya1 = fmaf(a1, ya0, fmaf(a2, x1,  va1));
      const float ya2 = fmaf(a1, ya1, fmaf(a2, ya0, va2));
      const float ya3 = fmaf(a1, ya2, fmaf(a2, ya1, va3));
      const float vb0 = g ? acc[4 * q + 0] : o0;
      const float vb1 = g ? acc[4 * q + 1] : o1;
      const float vb2 = g ? acc[4 * q + 2] : o2;
      const float vb3 = g ? acc[4 * q + 3] : o3;
      const float yb0 = fmaf(a1, ya3, fmaf(a2, ya2, vb0));
      const float yb1 = fmaf(a1, yb0, fmaf(a2, ya3, vb1));
      const float yb2 = fmaf(a1, yb1, fmaf(a2, yb0, vb2));
      const float yb3 = fmaf(a1, yb2, fmaf(a2, yb1, vb3));
      x2 = yb2; x1 = yb3;
      if (owned) {
        const int rb = 8 * q + 4 * g;   // lane half g writes rows rb..rb+3
        Tw[(rb + 0) * kTS + col] = g ? yb0 : ya0;
        Tw[(rb + 1) * kTS + col] = g ? yb1 : ya1;
        Tw[(rb + 2) * kTS + col] = g ? yb2 : ya2;
        Tw[(rb + 3) * kTS + col] = g ? yb3 : ya3;
      }
    }
    s1 = x1; s2 = x2;

    // ---- emit: 4x ds_read_b128 + 4x full-wave NON-TEMPORAL dwordx4 stores.
    // nt stores stream past L2 -> L2 stays dedicated to the u read stream.
    if (owned) {
      asm volatile("" ::: "memory");   // transpose writes before reads
#pragma unroll
      for (int p = 0; p < 4; ++p) {
        const f32x4_ma v = *(const f32x4_ma*)
            ((const char*)Tw + (8 * p + (lane >> 3)) * (kTS * 4) + (lane & 7) * 16);
        __builtin_nontemporal_store(
            v, (f32x4_ma*)(ob + (size_t)(tbase + 8 * p) * kCout + lane * 4));
      }
      asm volatile("" ::: "memory");   // reads before next tile's writes
    }

    // write-late stage refill (wave-local, in-order DS).
    if (!last) {
      asm volatile("" ::: "memory");   // this tile's ds_reads issue first
      stash(lane, n0);
      stash(lane + 64, n1);
      stash(lane + 128, n2);
      stash(lane + 192, n3);
      if (lane < 16) stash(lane + 256, n4);
      asm volatile("" ::: "memory");   // refill before next tile's ds_reads
    }
  }
}

}  // namespace

extern "C" void kernel_launch(void* const* d_in, const int* in_sizes, int n_in,
                              void* d_out, int out_size, void* d_ws, size_t ws_size,
                              hipStream_t stream) {
  const float* u  = (const float*)d_in[0];
  const float* x0 = (const float*)d_in[1];
  const float* a  = (const float*)d_in[2];
  const float* bb = (const float*)d_in[3];
  float* out = (float*)d_out;

  dim3 grid(kB * kChunks / kWpB);  // 4096 waves / 4 = 1024 blocks
  dim3 block(256);
  hipLaunchKernelGGL(mimo_mfma13, grid, block, 0, stream, u, x0, a, bb, out);
}